// Round 4
// baseline (131.587 us; speedup 1.0000x reference)
//
#include <hip/hip_runtime.h>
#include <hip/hip_bf16.h>

#define C 128
#define HW 4096
#define NPOS 65536
#define K 1024
#define MB 128            // positions per block
#define NBLK (NPOS/MB)    // 512
#define RS 136            // zt row stride in ushorts (272 B, 16B-aligned, conflict-light)
#define CHK 64            // codes per chunk
#define NCH (K/CHK)       // 16
#define IMG_RS 256        // bf16 image row stride bytes
#define CHB (CHK*IMG_RS)  // 16384 B per chunk in image

#define ZQ_OFF 0
#define LOSS_OFF 8388608
#define IDX_OFF 8388609
#define COMMIT_OFF 8454145
#define CODE_OFF 8454146

#define WS_EN_OFF 256     // d_ws byte offset: enorm1[1024] fp32 (||e||^2 + 1)
#define WS_IMG_OFF 8192   // d_ws byte offset: bf16 codebook image, 1024*256 B

typedef __bf16 bf16x8 __attribute__((ext_vector_type(8)));
typedef float f32x4 __attribute__((ext_vector_type(4)));

// Build bf16 codebook image (256 B rows) + enorm1[k] = ||e_k||^2 + 1.0
__global__ void vq_prep(const float* __restrict__ emb, unsigned char* __restrict__ img,
                        float* __restrict__ enorm1) {
    int t = threadIdx.x;
    int r = t >> 5, l = t & 31;          // 8 rows per block, 32 lanes per row
    int k = blockIdx.x * 8 + r;
    float4 v = ((const float4*)emb)[k * 32 + l];
    __hip_bfloat16 h0 = __float2bfloat16(v.x), h1 = __float2bfloat16(v.y),
                   h2 = __float2bfloat16(v.z), h3 = __float2bfloat16(v.w);
    ushort4 pk;
    pk.x = *(unsigned short*)&h0; pk.y = *(unsigned short*)&h1;
    pk.z = *(unsigned short*)&h2; pk.w = *(unsigned short*)&h3;
    *(ushort4*)(img + (size_t)k * IMG_RS + l * 8) = pk;
    float s = v.x * v.x + v.y * v.y + v.z * v.z + v.w * v.w;
    #pragma unroll
    for (int off = 16; off; off >>= 1) s += __shfl_xor(s, off);   // stays in 32-lane half
    if (l == 0) enorm1[k] = s + 1.0f;
}

__global__ __launch_bounds__(256, 2)
void vq_main(const float* __restrict__ z, const float* __restrict__ emb,
             const unsigned char* __restrict__ img, const float* __restrict__ enorm1,
             float* __restrict__ out, float* __restrict__ S, unsigned int* __restrict__ cnt) {
    __shared__ unsigned short zt[MB * RS];   // 34816 B
    __shared__ unsigned int wbest[4][MB];    // 2048 B
    __shared__ unsigned short idxs[MB];      // 256 B
    __shared__ float lred[4];

    const int t = threadIdx.x;
    const int w = t >> 6;
    const int lane = t & 63;
    const int nn = lane & 15;
    const int q = lane >> 4;

    const int n0g = blockIdx.x * MB;
    const int b = n0g >> 12;
    const int hw0 = n0g & (HW - 1);
    const float* zg = z + (size_t)b * C * HW + hw0;

    // stage z tile -> LDS bf16 [pos][c], 272 B rows (transpose for A-frags)
    {
        int pos = t & (MB - 1);
        int c0b = (t >> 7) * 64;
        #pragma unroll
        for (int i = 0; i < 16; ++i) {
            int c0 = c0b + i * 4;
            float f0 = zg[(size_t)(c0 + 0) * HW + pos];
            float f1 = zg[(size_t)(c0 + 1) * HW + pos];
            float f2 = zg[(size_t)(c0 + 2) * HW + pos];
            float f3 = zg[(size_t)(c0 + 3) * HW + pos];
            __hip_bfloat16 h0 = __float2bfloat16(f0), h1 = __float2bfloat16(f1),
                           h2 = __float2bfloat16(f2), h3 = __float2bfloat16(f3);
            ushort4 pk;
            pk.x = *(unsigned short*)&h0; pk.y = *(unsigned short*)&h1;
            pk.z = *(unsigned short*)&h2; pk.w = *(unsigned short*)&h3;
            *(ushort4*)&zt[pos * RS + c0] = pk;
        }
    }
    __syncthreads();

    // A fragments: 8 M-tiles x 4 K-steps, registers, reused across all 1024 codes
    bf16x8 a[8][4];
    #pragma unroll
    for (int mt = 0; mt < 8; ++mt)
        #pragma unroll
        for (int ks = 0; ks < 4; ++ks)
            a[mt][ks] = *(bf16x8*)&zt[(mt * 16 + nn) * RS + ks * 32 + q * 8];

    unsigned int best[8][4];
    #pragma unroll
    for (int mt = 0; mt < 8; ++mt)
        #pragma unroll
        for (int r = 0; r < 4; ++r) best[mt][r] = 0xFFFFFFFFu;

    // this wave's B row: code = w*16 + nn (per chunk); direct global, no LDS, no barriers
    const unsigned char* gB = img + (size_t)(w * 16 + nn) * IMG_RS + q * 16;
    const float* gE = enorm1 + w * 16 + nn;

    bf16x8 bcur[4], bnxt[4];
    #pragma unroll
    for (int ks = 0; ks < 4; ++ks)
        bcur[ks] = *(const bf16x8*)(gB + ks * 64);

    for (int ch = 0; ch < NCH; ++ch) {
        if (ch + 1 < NCH) {
            const unsigned char* src = gB + (size_t)(ch + 1) * CHB;
            #pragma unroll
            for (int ks = 0; ks < 4; ++ks)
                bnxt[ks] = *(const bf16x8*)(src + ks * 64);
        }
        const float en1 = gE[ch * CHK];            // ||e||^2 + 1 (L2-hot scalar-ish load)
        const unsigned int code = (unsigned int)(ch * CHK + w * 16 + nn);

        f32x4 acc[8];
        #pragma unroll
        for (int mt = 0; mt < 8; ++mt) acc[mt] = (f32x4){0.f, 0.f, 0.f, 0.f};
        #pragma unroll
        for (int ks = 0; ks < 4; ++ks)
            #pragma unroll
            for (int mt = 0; mt < 8; ++mt)
                acc[mt] = __builtin_amdgcn_mfma_f32_16x16x32_bf16(a[mt][ks], bcur[ks], acc[mt], 0, 0, 0);

        // packed argmin: s = (||e||^2+1) - 2*dot  in (0,2) always; u32 min == float min,
        // low-10-bit code field gives np's tie-break (lowest index).
        #pragma unroll
        for (int mt = 0; mt < 8; ++mt)
            #pragma unroll
            for (int r = 0; r < 4; ++r) {
                float s = fmaf(acc[mt][r], -2.0f, en1);
                unsigned int u = (__float_as_uint(s) & ~1023u) | code;
                best[mt][r] = min(best[mt][r], u);
            }
        #pragma unroll
        for (int ks = 0; ks < 4; ++ks) bcur[ks] = bnxt[ks];
    }

    // reduce over the 16 code-columns (xor within quad-row group)
    #pragma unroll
    for (int mt = 0; mt < 8; ++mt)
        #pragma unroll
        for (int r = 0; r < 4; ++r) {
            unsigned int v = best[mt][r];
            v = min(v, (unsigned int)__shfl_xor((int)v, 1));
            v = min(v, (unsigned int)__shfl_xor((int)v, 2));
            v = min(v, (unsigned int)__shfl_xor((int)v, 4));
            v = min(v, (unsigned int)__shfl_xor((int)v, 8));
            if (nn == 0) wbest[w][mt * 16 + q * 4 + r] = v;
        }
    __syncthreads();

    if (t < MB) {
        unsigned int v = min(min(wbest[0][t], wbest[1][t]), min(wbest[2][t], wbest[3][t]));
        unsigned int code = v & 1023u;
        idxs[t] = (unsigned short)code;
        out[IDX_OFF + n0g + t] = (float)code;
    }
    __syncthreads();

    // epilogue: exact fp32 gather of chosen rows, z_q store, loss
    {
        int pos = t & (MB - 1);
        int c0b = (t >> 7) * 64;
        int myidx = idxs[pos];
        const float* erow = emb + (size_t)myidx * C;
        float* og = out + ZQ_OFF + (size_t)b * C * HW + hw0;
        float ls = 0.f;
        #pragma unroll
        for (int i = 0; i < 16; ++i) {
            int c0 = c0b + i * 4;
            float4 ev = *(const float4*)&erow[c0];
            ushort4 zz = *(ushort4*)&zt[pos * RS + c0];
            float z0 = __uint_as_float((unsigned int)zz.x << 16);
            float z1 = __uint_as_float((unsigned int)zz.y << 16);
            float z2 = __uint_as_float((unsigned int)zz.z << 16);
            float z3 = __uint_as_float((unsigned int)zz.w << 16);
            float d0 = z0 - ev.x, d1 = z1 - ev.y, d2 = z2 - ev.z, d3 = z3 - ev.w;
            ls += d0 * d0 + d1 * d1 + d2 * d2 + d3 * d3;
            og[(size_t)(c0 + 0) * HW + pos] = ev.x;
            og[(size_t)(c0 + 1) * HW + pos] = ev.y;
            og[(size_t)(c0 + 2) * HW + pos] = ev.z;
            og[(size_t)(c0 + 3) * HW + pos] = ev.w;
        }
        #pragma unroll
        for (int off = 32; off; off >>= 1) ls += __shfl_down(ls, off);
        if (lane == 0) lred[w] = ls;
    }
    __syncthreads();

    // fused finalization: last block writes the 3 scalars
    if (t == 0) {
        atomicAdd(S, lred[0] + lred[1] + lred[2] + lred[3]);
        __threadfence();
        unsigned int old = atomicAdd(cnt, 1u);
        if (old == NBLK - 1) {
            float s = atomicAdd(S, 0.0f);   // coherent read of final sum
            out[LOSS_OFF] = 1.25f * s;
            out[COMMIT_OFF] = 0.25f * s;
            out[CODE_OFF] = s;
        }
    }
}

extern "C" void kernel_launch(void* const* d_in, const int* in_sizes, int n_in,
                              void* d_out, int out_size, void* d_ws, size_t ws_size,
                              hipStream_t stream) {
    const float* z = (const float*)d_in[0];
    const float* emb = (const float*)d_in[1];
    float* out = (float*)d_out;
    float* S = (float*)d_ws;                                    // [0]
    unsigned int* cnt = (unsigned int*)d_ws + 1;                // [1]
    float* enorm1 = (float*)((unsigned char*)d_ws + WS_EN_OFF); // 4 KB
    unsigned char* img = (unsigned char*)d_ws + WS_IMG_OFF;     // 256 KB

    hipMemsetAsync(d_ws, 0, 64, stream);
    vq_prep<<<K / 8, 256, 0, stream>>>(emb, img, enorm1);
    vq_main<<<NBLK, 256, 0, stream>>>(z, emb, img, enorm1, out, S, cnt);
}